// Round 1
// baseline (241.865 us; speedup 1.0000x reference)
//
#include <hip/hip_runtime.h>
#include <hip/hip_bf16.h>

#define SEQ 2048
#define DIM 1024
#define NH 16
#define HD 64
#define MTOT 4096  // B*S

typedef __attribute__((ext_vector_type(8))) short bf16x8;
typedef __attribute__((ext_vector_type(4))) float f32x4;

typedef const __attribute__((address_space(1))) void* gptr_t;
typedef __attribute__((address_space(3))) void* sptr_t;

static __device__ __forceinline__ unsigned short f2bf(float f) {
    unsigned int u = __builtin_bit_cast(unsigned int, f);
    return (unsigned short)((u + 0x7FFFu + ((u >> 16) & 1u)) >> 16);
}

// ---------------- fp32 -> bf16 cast ----------------
__global__ void cast_kernel(const float* __restrict__ in, unsigned short* __restrict__ out, int n) {
    int i = (blockIdx.x * 256 + threadIdx.x) * 4;
    if (i < n) {
        float4 v = *reinterpret_cast<const float4*>(in + i);
        ushort4 o;
        o.x = f2bf(v.x); o.y = f2bf(v.y); o.z = f2bf(v.z); o.w = f2bf(v.w);
        *reinterpret_cast<ushort4*>(out + i) = o;
    }
}

// ---------------- NT GEMM: C[M,N] = A[M,K] * B[N,K]^T (bf16 in) ----------------
// MODE 0: z in {0,1,2} selects B/W and dst (q/k/v); scatter to [B,H,S,hd], Q scaled 0.125.
// MODE 1: fp32 out + bias.
template<int MODE>
__global__ __launch_bounds__(256) void gemm_nt(
    const unsigned short* __restrict__ A,
    const unsigned short* __restrict__ B0,
    const unsigned short* __restrict__ B1,
    const unsigned short* __restrict__ B2,
    unsigned short* __restrict__ D0,
    unsigned short* __restrict__ D1,
    unsigned short* __restrict__ D2,
    float* __restrict__ Df,
    const float* __restrict__ bias)
{
    constexpr int K = DIM;
    __shared__ __align__(16) unsigned short Asm[128 * 32];
    __shared__ __align__(16) unsigned short Bsm[128 * 32];

    const int tid = threadIdx.x;
    const int wave = tid >> 6, lane = tid & 63;
    const int wm = wave >> 1, wn = wave & 1;
    const int m0 = blockIdx.y * 128, n0 = blockIdx.x * 128;
    const int fr = lane & 15;

    const unsigned short* Bsel = (MODE == 1 || blockIdx.z == 0) ? B0 : (blockIdx.z == 1 ? B1 : B2);

    // staging geometry: LDS tile [128 rows][32 shorts] = 64B rows, 4x16B chunks.
    // content(row, ch) = global chunk (ch ^ ((row>>1)&3)) of row  -> 2-way max on frag reads
    const int srow = wave * 32 + (lane >> 2);                 // +c*16
    const int schunk = (lane & 3) ^ ((lane >> 3) & 3);        // (row>>1)&3 == (lane>>3)&3
    const size_t abase = (size_t)(m0 + srow) * K + (size_t)schunk * 8;
    const size_t bbase = (size_t)(n0 + srow) * K + (size_t)schunk * 8;

    f32x4 acc[4][4] = {};

    for (int k0 = 0; k0 < K; k0 += 32) {
        #pragma unroll
        for (int c = 0; c < 2; ++c) {
            __builtin_amdgcn_global_load_lds(
                (gptr_t)(A + abase + (size_t)c * 16 * K + k0),
                (sptr_t)((char*)Asm + wave * 2048 + c * 1024), 16, 0, 0);
            __builtin_amdgcn_global_load_lds(
                (gptr_t)(Bsel + bbase + (size_t)c * 16 * K + k0),
                (sptr_t)((char*)Bsm + wave * 2048 + c * 1024), 16, 0, 0);
        }
        __syncthreads();

        bf16x8 af[4], bf[4];
        const int ca = ((lane >> 4) ^ ((fr >> 1) & 3)) * 16;  // swizzled chunk byte offset
        #pragma unroll
        for (int i = 0; i < 4; ++i) {
            int ra = wm * 64 + i * 16 + fr;
            int rb = wn * 64 + i * 16 + fr;
            af[i] = *(const bf16x8*)((const char*)Asm + ra * 64 + ca);
            bf[i] = *(const bf16x8*)((const char*)Bsm + rb * 64 + ca);
        }
        #pragma unroll
        for (int i = 0; i < 4; ++i)
            #pragma unroll
            for (int j = 0; j < 4; ++j)
                acc[i][j] = __builtin_amdgcn_mfma_f32_16x16x32_bf16(af[i], bf[j], acc[i][j], 0, 0, 0);
        __syncthreads();
    }

    if (MODE == 0) {
        unsigned short* Dst = (blockIdx.z == 0) ? D0 : (blockIdx.z == 1 ? D1 : D2);
        const float scale = (blockIdx.z == 0) ? 0.125f : 1.0f;
        #pragma unroll
        for (int i = 0; i < 4; ++i)
            #pragma unroll
            for (int j = 0; j < 4; ++j)
                #pragma unroll
                for (int r = 0; r < 4; ++r) {
                    int m = m0 + wm * 64 + i * 16 + (lane >> 4) * 4 + r;
                    int n = n0 + wn * 64 + j * 16 + fr;
                    int b = m >> 11, s = m & 2047, h = n >> 6, dh = n & 63;
                    Dst[(((size_t)(b * NH + h)) * SEQ + s) * HD + dh] = f2bf(acc[i][j][r] * scale);
                }
    } else {
        #pragma unroll
        for (int i = 0; i < 4; ++i)
            #pragma unroll
            for (int j = 0; j < 4; ++j)
                #pragma unroll
                for (int r = 0; r < 4; ++r) {
                    int m = m0 + wm * 64 + i * 16 + (lane >> 4) * 4 + r;
                    int n = n0 + wn * 64 + j * 16 + fr;
                    Df[(size_t)m * DIM + n] = acc[i][j][r] + bias[n];
                }
    }
}

// ---------------- flash attention (non-causal), Q pre-scaled ----------------
// grid: (SEQ/64, B*NH); block 256. wave w owns q-rows [q0+16w, q0+16w+16).
__global__ __launch_bounds__(256) void attn_kernel(
    const unsigned short* __restrict__ Q,
    const unsigned short* __restrict__ Kg,
    const unsigned short* __restrict__ Vg,
    unsigned short* __restrict__ O)
{
    __shared__ __align__(16) unsigned short Klds[64 * 64];
    __shared__ __align__(16) unsigned short Vt[64 * 64];
    __shared__ __align__(16) unsigned short Plds[4][16 * 64];

    const int tid = threadIdx.x, wave = tid >> 6, lane = tid & 63;
    const int bh = blockIdx.y;
    const int q0 = blockIdx.x * 64;
    const unsigned short* Qh = Q + (size_t)bh * SEQ * HD;
    const unsigned short* Kh = Kg + (size_t)bh * SEQ * HD;
    const unsigned short* Vh = Vg + (size_t)bh * SEQ * HD;
    const int fr = lane & 15;
    const int fc = (lane >> 4) * 8;

    bf16x8 qf[2];
    {
        int qrow = q0 + wave * 16 + fr;
        qf[0] = *(const bf16x8*)&Qh[(size_t)qrow * HD + fc];
        qf[1] = *(const bf16x8*)&Qh[(size_t)qrow * HD + 32 + fc];
    }
    f32x4 o_acc[4] = {};
    float mrow[4], lrow[4];
    #pragma unroll
    for (int r = 0; r < 4; ++r) { mrow[r] = -1e30f; lrow[r] = 0.f; }

    // K staging: LDS [64 rows][64 shorts]=128B rows, 8x16B chunks.
    // content(row, ch) = global chunk (ch ^ (row&7))
    const int krow = wave * 16 + (lane >> 3);      // +c*8
    const int kchunk = (lane & 7) ^ (lane >> 3);   // row&7 == lane>>3
    const size_t kbo = (size_t)krow * HD + (size_t)kchunk * 8;

    for (int t = 0; t < SEQ; t += 64) {
        #pragma unroll
        for (int c = 0; c < 2; ++c)
            __builtin_amdgcn_global_load_lds(
                (gptr_t)(Kh + (size_t)t * HD + kbo + (size_t)c * 8 * HD),
                (sptr_t)((char*)Klds + wave * 2048 + c * 1024), 16, 0, 0);
        // V transposed + swizzled: Vt content(d, ch) = V kv-chunk (ch ^ (d&7))
        #pragma unroll
        for (int it = 0; it < 2; ++it) {
            int ch = tid + it * 256;      // 0..511 16B-chunks of the 64x64 tile
            int kv = ch >> 3, d0 = (ch & 7) * 8;
            bf16x8 vv = *(const bf16x8*)&Vh[(size_t)(t + kv) * HD + d0];
            #pragma unroll
            for (int j = 0; j < 8; ++j) {
                int d = d0 + j;
                int byteoff = d * 128 + (((kv >> 3) ^ (d & 7)) * 16) + (kv & 7) * 2;
                *(unsigned short*)((char*)Vt + byteoff) = (unsigned short)vv[j];
            }
        }
        __syncthreads();

        // S = Q K^T  (A=Q rows, B=K^T via identical frag load)
        f32x4 s[4];
        #pragma unroll
        for (int kt = 0; kt < 4; ++kt) {
            int row = kt * 16 + fr;
            int x7 = row & 7;
            bf16x8 k0 = *(const bf16x8*)((const char*)Klds + row * 128 + (((lane >> 4) ^ x7) * 16));
            bf16x8 k1 = *(const bf16x8*)((const char*)Klds + row * 128 + (((4 + (lane >> 4)) ^ x7) * 16));
            f32x4 z = {};
            z = __builtin_amdgcn_mfma_f32_16x16x32_bf16(qf[0], k0, z, 0, 0, 0);
            s[kt] = __builtin_amdgcn_mfma_f32_16x16x32_bf16(qf[1], k1, z, 0, 0, 0);
        }

        // online softmax (rows live in lanes sharing lane>>4; reduce over low 4 bits)
        float pmax[4];
        #pragma unroll
        for (int r = 0; r < 4; ++r)
            pmax[r] = fmaxf(fmaxf(s[0][r], s[1][r]), fmaxf(s[2][r], s[3][r]));
        #pragma unroll
        for (int d = 1; d < 16; d <<= 1)
            #pragma unroll
            for (int r = 0; r < 4; ++r)
                pmax[r] = fmaxf(pmax[r], __shfl_xor(pmax[r], d));
        float fac[4];
        #pragma unroll
        for (int r = 0; r < 4; ++r) {
            float mn = fmaxf(mrow[r], pmax[r]);
            fac[r] = __expf(mrow[r] - mn);
            mrow[r] = mn;
        }
        #pragma unroll
        for (int dt = 0; dt < 4; ++dt)
            #pragma unroll
            for (int r = 0; r < 4; ++r)
                o_acc[dt][r] *= fac[r];
        float psum[4] = {0.f, 0.f, 0.f, 0.f};
        #pragma unroll
        for (int kt = 0; kt < 4; ++kt)
            #pragma unroll
            for (int r = 0; r < 4; ++r) {
                float p = __expf(s[kt][r] - mrow[r]);
                s[kt][r] = p;
                psum[r] += p;
            }
        #pragma unroll
        for (int d = 1; d < 16; d <<= 1)
            #pragma unroll
            for (int r = 0; r < 4; ++r)
                psum[r] += __shfl_xor(psum[r], d);
        #pragma unroll
        for (int r = 0; r < 4; ++r)
            lrow[r] = lrow[r] * fac[r] + psum[r];

        // P -> per-wave LDS (bf16, swizzled): content(q, ch) = P kv-chunk (ch ^ (q&7))
        #pragma unroll
        for (int kt = 0; kt < 4; ++kt)
            #pragma unroll
            for (int r = 0; r < 4; ++r) {
                int qq = (lane >> 4) * 4 + r;
                int kv = kt * 16 + fr;
                int byteoff = qq * 128 + (((kv >> 3) ^ (qq & 7)) * 16) + (kv & 7) * 2;
                *(unsigned short*)((char*)&Plds[wave][0] + byteoff) = f2bf(s[kt][r]);
            }
        asm volatile("s_waitcnt lgkmcnt(0)" ::: "memory");
        __builtin_amdgcn_sched_barrier(0);

        // O += P V
        #pragma unroll
        for (int dt = 0; dt < 4; ++dt) {
            int vrow = dt * 16 + fr;
            int x7 = vrow & 7;
            #pragma unroll
            for (int c = 0; c < 2; ++c) {
                int chp = c * 4 + (lane >> 4);
                bf16x8 pa = *(const bf16x8*)((const char*)&Plds[wave][0] + fr * 128 + ((chp ^ (fr & 7)) * 16));
                bf16x8 bv = *(const bf16x8*)((const char*)Vt + vrow * 128 + ((chp ^ x7) * 16));
                o_acc[dt] = __builtin_amdgcn_mfma_f32_16x16x32_bf16(pa, bv, o_acc[dt], 0, 0, 0);
            }
        }
        __syncthreads();
    }

    const int b = bh >> 4, h = bh & 15;
    #pragma unroll
    for (int r = 0; r < 4; ++r) {
        float inv = 1.0f / lrow[r];
        int qq = q0 + wave * 16 + (lane >> 4) * 4 + r;
        #pragma unroll
        for (int dt = 0; dt < 4; ++dt)
            O[((size_t)(b * SEQ + qq)) * DIM + h * HD + dt * 16 + fr] = f2bf(o_acc[dt][r] * inv);
    }
}

extern "C" void kernel_launch(void* const* d_in, const int* in_sizes, int n_in,
                              void* d_out, int out_size, void* d_ws, size_t ws_size,
                              hipStream_t stream) {
    const float* x  = (const float*)d_in[0];
    const float* Wq = (const float*)d_in[1];
    const float* Wk = (const float*)d_in[2];
    const float* Wv = (const float*)d_in[3];
    const float* Wo = (const float*)d_in[4];
    const float* bo = (const float*)d_in[5];
    float* out = (float*)d_out;

    unsigned short* ws = (unsigned short*)d_ws;
    unsigned short* xb  = ws;
    unsigned short* wqb = xb + (size_t)MTOT * DIM;
    unsigned short* wkb = wqb + (size_t)DIM * DIM;
    unsigned short* wvb = wkb + (size_t)DIM * DIM;
    unsigned short* wob = wvb + (size_t)DIM * DIM;
    unsigned short* qb  = wob + (size_t)DIM * DIM;
    unsigned short* kb  = qb + (size_t)MTOT * DIM;
    unsigned short* vb  = kb + (size_t)MTOT * DIM;
    unsigned short* ob  = vb + (size_t)MTOT * DIM;

    cast_kernel<<<dim3(MTOT * DIM / 1024), 256, 0, stream>>>(x, xb, MTOT * DIM);
    cast_kernel<<<dim3(DIM * DIM / 1024), 256, 0, stream>>>(Wq, wqb, DIM * DIM);
    cast_kernel<<<dim3(DIM * DIM / 1024), 256, 0, stream>>>(Wk, wkb, DIM * DIM);
    cast_kernel<<<dim3(DIM * DIM / 1024), 256, 0, stream>>>(Wv, wvb, DIM * DIM);
    cast_kernel<<<dim3(DIM * DIM / 1024), 256, 0, stream>>>(Wo, wob, DIM * DIM);

    gemm_nt<0><<<dim3(DIM / 128, MTOT / 128, 3), 256, 0, stream>>>(
        xb, wqb, wkb, wvb, qb, kb, vb, nullptr, nullptr);

    attn_kernel<<<dim3(SEQ / 64, 2 * NH), 256, 0, stream>>>(qb, kb, vb, ob);

    gemm_nt<1><<<dim3(DIM / 128, MTOT / 128, 1), 256, 0, stream>>>(
        ob, wob, nullptr, nullptr, nullptr, nullptr, nullptr, out, bo);
}

// Round 2
// 139.336 us; speedup vs baseline: 1.7358x; 1.7358x over previous
//
#include <hip/hip_runtime.h>
#include <hip/hip_bf16.h>

#define SEQ 2048
#define DIM 1024
#define NH 16
#define HD 64
#define MTOT 4096  // B*S

typedef __attribute__((ext_vector_type(8))) short bf16x8;
typedef __attribute__((ext_vector_type(4))) float f32x4;
typedef __attribute__((ext_vector_type(16))) float f32x16;
typedef __attribute__((ext_vector_type(4))) unsigned int u32x4;
typedef __attribute__((ext_vector_type(2))) unsigned int u32x2;

typedef const __attribute__((address_space(1))) void* gptr_t;
typedef __attribute__((address_space(3))) void* sptr_t;

static __device__ __forceinline__ unsigned short f2bf(float f) {
    unsigned int u = __builtin_bit_cast(unsigned int, f);
    return (unsigned short)((u + 0x7FFFu + ((u >> 16) & 1u)) >> 16);
}

#define CVTPK(d, x, y) asm("v_cvt_pk_bf16_f32 %0, %1, %2" : "=v"(d) : "v"(x), "v"(y))
#define PLSWAP(a, b) asm("v_permlane32_swap_b32 %0, %1" : "+v"(a), "+v"(b))

// ---------------- fp32 -> bf16 cast ----------------
__global__ void cast_kernel(const float* __restrict__ in, unsigned short* __restrict__ out, int n) {
    int i = (blockIdx.x * 256 + threadIdx.x) * 4;
    if (i < n) {
        float4 v = *reinterpret_cast<const float4*>(in + i);
        ushort4 o;
        o.x = f2bf(v.x); o.y = f2bf(v.y); o.z = f2bf(v.z); o.w = f2bf(v.w);
        *reinterpret_cast<ushort4*>(out + i) = o;
    }
}

// ---------------- NT GEMM: C[M,N] = A[M,K] * B[N,K]^T (bf16 in) ----------------
template<int MODE>
__global__ __launch_bounds__(256) void gemm_nt(
    const unsigned short* __restrict__ A,
    const unsigned short* __restrict__ B0,
    const unsigned short* __restrict__ B1,
    const unsigned short* __restrict__ B2,
    unsigned short* __restrict__ D0,
    unsigned short* __restrict__ D1,
    unsigned short* __restrict__ D2,
    float* __restrict__ Df,
    const float* __restrict__ bias)
{
    constexpr int K = DIM;
    __shared__ __align__(16) unsigned short Asm[128 * 32];
    __shared__ __align__(16) unsigned short Bsm[128 * 32];

    const int tid = threadIdx.x;
    const int wave = tid >> 6, lane = tid & 63;
    const int wm = wave >> 1, wn = wave & 1;
    const int m0 = blockIdx.y * 128, n0 = blockIdx.x * 128;
    const int fr = lane & 15;

    const unsigned short* Bsel = (MODE == 1 || blockIdx.z == 0) ? B0 : (blockIdx.z == 1 ? B1 : B2);

    const int srow = wave * 32 + (lane >> 2);
    const int schunk = (lane & 3) ^ ((lane >> 3) & 3);
    const size_t abase = (size_t)(m0 + srow) * K + (size_t)schunk * 8;
    const size_t bbase = (size_t)(n0 + srow) * K + (size_t)schunk * 8;

    f32x4 acc[4][4] = {};

    for (int k0 = 0; k0 < K; k0 += 32) {
        #pragma unroll
        for (int c = 0; c < 2; ++c) {
            __builtin_amdgcn_global_load_lds(
                (gptr_t)(A + abase + (size_t)c * 16 * K + k0),
                (sptr_t)((char*)Asm + wave * 2048 + c * 1024), 16, 0, 0);
            __builtin_amdgcn_global_load_lds(
                (gptr_t)(Bsel + bbase + (size_t)c * 16 * K + k0),
                (sptr_t)((char*)Bsm + wave * 2048 + c * 1024), 16, 0, 0);
        }
        __syncthreads();

        bf16x8 af[4], bf[4];
        const int ca = ((lane >> 4) ^ ((fr >> 1) & 3)) * 16;
        #pragma unroll
        for (int i = 0; i < 4; ++i) {
            int ra = wm * 64 + i * 16 + fr;
            int rb = wn * 64 + i * 16 + fr;
            af[i] = *(const bf16x8*)((const char*)Asm + ra * 64 + ca);
            bf[i] = *(const bf16x8*)((const char*)Bsm + rb * 64 + ca);
        }
        #pragma unroll
        for (int i = 0; i < 4; ++i)
            #pragma unroll
            for (int j = 0; j < 4; ++j)
                acc[i][j] = __builtin_amdgcn_mfma_f32_16x16x32_bf16(af[i], bf[j], acc[i][j], 0, 0, 0);
        __syncthreads();
    }

    if (MODE == 0) {
        unsigned short* Dst = (blockIdx.z == 0) ? D0 : (blockIdx.z == 1 ? D1 : D2);
        // Q gets 1/8 * log2(e) folded in (softmax runs in exp2 domain)
        const float scale = (blockIdx.z == 0) ? 0.1803368787f : 1.0f;
        #pragma unroll
        for (int i = 0; i < 4; ++i)
            #pragma unroll
            for (int j = 0; j < 4; ++j)
                #pragma unroll
                for (int r = 0; r < 4; ++r) {
                    int m = m0 + wm * 64 + i * 16 + (lane >> 4) * 4 + r;
                    int n = n0 + wn * 64 + j * 16 + fr;
                    int b = m >> 11, s = m & 2047, h = n >> 6, dh = n & 63;
                    Dst[(((size_t)(b * NH + h)) * SEQ + s) * HD + dh] = f2bf(acc[i][j][r] * scale);
                }
    } else {
        #pragma unroll
        for (int i = 0; i < 4; ++i)
            #pragma unroll
            for (int j = 0; j < 4; ++j)
                #pragma unroll
                for (int r = 0; r < 4; ++r) {
                    int m = m0 + wm * 64 + i * 16 + (lane >> 4) * 4 + r;
                    int n = n0 + wn * 64 + j * 16 + fr;
                    Df[(size_t)m * DIM + n] = acc[i][j][r] + bias[n];
                }
    }
}

// ---------------- flash attention, swapped-operand 32x32x16 (Q pre-scaled by 0.125*log2e) ----------------
// grid: 256 blocks (1/CU), 512 threads (8 waves x 32 q-rows = 256 q/block).
// XCD-aware decode: xcd = bid&7 owns bh in [4*xcd, 4*xcd+4).
__global__ __launch_bounds__(512, 2) void attn_kernel(
    const unsigned short* __restrict__ Q,
    const unsigned short* __restrict__ Kg,
    const unsigned short* __restrict__ Vg,
    unsigned short* __restrict__ O)
{
    // 132-byte (33-word) row stride: odd word stride -> conflict-free b32 phases
    __shared__ __align__(16) unsigned short Ksm[2][64 * 66];  // [kv][d]
    __shared__ __align__(16) unsigned short Vsm[2][64 * 66];  // [d][kv] (transposed)

    const int tid = threadIdx.x;
    const int wave = tid >> 6, lane = tid & 63;
    const int lq = lane & 31, hi = lane >> 5;

    const int bid = blockIdx.x;
    const int xcd = bid & 7, slot = bid >> 3;
    const int bh = xcd * 4 + (slot & 3);
    const int q0 = (slot >> 2) * 256;

    const unsigned short* Qh = Q + (size_t)bh * SEQ * HD;
    const unsigned short* Kh = Kg + (size_t)bh * SEQ * HD;
    const unsigned short* Vh = Vg + (size_t)bh * SEQ * HD;

    // Q row in registers: qf[dch] = Q[qrow][dch*16 + hi*8 .. +8)
    const int qrow = q0 + wave * 32 + lq;
    bf16x8 qf[4];
    #pragma unroll
    for (int dch = 0; dch < 4; ++dch)
        qf[dch] = *(const bf16x8*)(Qh + (size_t)qrow * HD + dch * 16 + hi * 8);

    f32x16 ot0 = {}, ot1 = {};          // O^T rows d=0..31 / 32..63, col q=lq
    float m = -1e30f, l = 0.f;

    // staging thread maps
    const int krow_s = tid >> 3, kch_s = tid & 7;              // K: row, 16B chunk
    const int kvp_s = tid >> 4, sub_s = tid & 1;               // V: kv pair, parity
    const int dch_s = (tid >> 1) & 7;                          // V: 8-d chunk

    bf16x8 sk, sv;
    auto stage_load = [&](int t64) {
        sk = *(const bf16x8*)(Kh + (size_t)(t64 + krow_s) * HD + kch_s * 8);
        sv = *(const bf16x8*)(Vh + (size_t)(t64 + 2 * kvp_s + sub_s) * HD + dch_s * 8);
    };
    auto stage_write = [&](int buf) {
        // K row-major, byte = 132*row + 16*ch (+4j)
        u32x4 kw = __builtin_bit_cast(u32x4, sk);
        unsigned* kp = (unsigned*)((char*)&Ksm[buf][0] + 132 * krow_s + 16 * kch_s);
        kp[0] = kw[0]; kp[1] = kw[1]; kp[2] = kw[2]; kp[3] = kw[3];
        // V transposed: word(d, kvp) = (V[2kvp][d], V[2kvp+1][d])
        u32x4 vw = __builtin_bit_cast(u32x4, sv);
        unsigned p0 = (unsigned)__shfl_xor((int)vw[0], 1);
        unsigned p1 = (unsigned)__shfl_xor((int)vw[1], 1);
        unsigned p2 = (unsigned)__shfl_xor((int)vw[2], 1);
        unsigned p3 = (unsigned)__shfl_xor((int)vw[3], 1);
        unsigned ea0 = sub_s ? p2 : vw[0];   // even-kv words for this lane's d range
        unsigned ea1 = sub_s ? p3 : vw[1];
        unsigned eb0 = sub_s ? vw[2] : p0;   // odd-kv words
        unsigned eb1 = sub_s ? vw[3] : p1;
        unsigned* vp = (unsigned*)&Vsm[buf][0];
        const int dbase = dch_s * 8 + sub_s * 4;
        vp[33 * (dbase + 0) + kvp_s] = (ea0 & 0xffffu) | (eb0 << 16);
        vp[33 * (dbase + 1) + kvp_s] = (ea0 >> 16) | (eb0 & 0xffff0000u);
        vp[33 * (dbase + 2) + kvp_s] = (ea1 & 0xffffu) | (eb1 << 16);
        vp[33 * (dbase + 3) + kvp_s] = (ea1 >> 16) | (eb1 & 0xffff0000u);
    };

    stage_load(0);
    stage_write(0);
    __syncthreads();

    int cur = 0;
    #pragma unroll 1
    for (int t = 0; t < SEQ / 64; ++t) {
        if (t + 1 < SEQ / 64) stage_load((t + 1) * 64);   // T14: issue loads early

        const char* Kb = (const char*)&Ksm[cur][0];
        const char* Vb = (const char*)&Vsm[cur][0];

        // S^T = mfma(K, Q^T): col = q = lq, row = kv = (r&3)+8*(r>>2)+4*hi (+32 for st1)
        f32x16 st0 = {}, st1 = {};
        __builtin_amdgcn_s_setprio(1);
        #pragma unroll
        for (int dch = 0; dch < 4; ++dch) {
            const unsigned* a0 = (const unsigned*)(Kb + 132 * lq + 32 * dch + 16 * hi);
            const unsigned* a1 = (const unsigned*)(Kb + 132 * (32 + lq) + 32 * dch + 16 * hi);
            u32x4 f0 = {a0[0], a0[1], a0[2], a0[3]};
            u32x4 f1 = {a1[0], a1[1], a1[2], a1[3]};
            st0 = __builtin_amdgcn_mfma_f32_32x32x16_bf16(__builtin_bit_cast(bf16x8, f0), qf[dch], st0, 0, 0, 0);
            st1 = __builtin_amdgcn_mfma_f32_32x32x16_bf16(__builtin_bit_cast(bf16x8, f1), qf[dch], st1, 0, 0, 0);
        }
        __builtin_amdgcn_s_setprio(0);

        // in-register online softmax (exp2 domain), T13 defer-max
        float pm = st0[0];
        #pragma unroll
        for (int r = 1; r < 16; ++r) pm = fmaxf(pm, st0[r]);
        #pragma unroll
        for (int r = 0; r < 16; ++r) pm = fmaxf(pm, st1[r]);
        pm = fmaxf(pm, __shfl_xor(pm, 32));
        if (__any(pm > m + 8.0f)) {
            float mn = fmaxf(m, pm);
            float fc = exp2f(m - mn);
            l *= fc;
            #pragma unroll
            for (int r = 0; r < 16; ++r) { ot0[r] *= fc; ot1[r] *= fc; }
            m = mn;
        }
        float ps = 0.f;
        #pragma unroll
        for (int r = 0; r < 16; ++r) { st0[r] = exp2f(st0[r] - m); ps += st0[r]; }
        #pragma unroll
        for (int r = 0; r < 16; ++r) { st1[r] = exp2f(st1[r] - m); ps += st1[r]; }
        ps += __shfl_xor(ps, 32);
        l += ps;

        // T12: P -> bf16 B-frags fully in-register (cvt_pk + permlane32_swap)
        bf16x8 pf0, pf1, pf2, pf3;
        {
            unsigned w0, w1, w2, w3, w4, w5, w6, w7;
            CVTPK(w0, st0[0], st0[1]);   CVTPK(w1, st0[2], st0[3]);
            CVTPK(w2, st0[4], st0[5]);   CVTPK(w3, st0[6], st0[7]);
            CVTPK(w4, st0[8], st0[9]);   CVTPK(w5, st0[10], st0[11]);
            CVTPK(w6, st0[12], st0[13]); CVTPK(w7, st0[14], st0[15]);
            PLSWAP(w0, w2); PLSWAP(w1, w3); PLSWAP(w4, w6); PLSWAP(w5, w7);
            u32x4 uA = {w0, w1, w2, w3}, uB = {w4, w5, w6, w7};
            pf0 = __builtin_bit_cast(bf16x8, uA);
            pf1 = __builtin_bit_cast(bf16x8, uB);
        }
        {
            unsigned w0, w1, w2, w3, w4, w5, w6, w7;
            CVTPK(w0, st1[0], st1[1]);   CVTPK(w1, st1[2], st1[3]);
            CVTPK(w2, st1[4], st1[5]);   CVTPK(w3, st1[6], st1[7]);
            CVTPK(w4, st1[8], st1[9]);   CVTPK(w5, st1[10], st1[11]);
            CVTPK(w6, st1[12], st1[13]); CVTPK(w7, st1[14], st1[15]);
            PLSWAP(w0, w2); PLSWAP(w1, w3); PLSWAP(w4, w6); PLSWAP(w5, w7);
            u32x4 uA = {w0, w1, w2, w3}, uB = {w4, w5, w6, w7};
            pf2 = __builtin_bit_cast(bf16x8, uA);
            pf3 = __builtin_bit_cast(bf16x8, uB);
        }

        // O^T += mfma(V^T, P^T)
        __builtin_amdgcn_s_setprio(1);
        #pragma unroll
        for (int kc = 0; kc < 4; ++kc) {
            const unsigned* v0 = (const unsigned*)(Vb + 132 * lq + 32 * kc + 16 * hi);
            const unsigned* v1 = (const unsigned*)(Vb + 132 * (32 + lq) + 32 * kc + 16 * hi);
            u32x4 g0 = {v0[0], v0[1], v0[2], v0[3]};
            u32x4 g1 = {v1[0], v1[1], v1[2], v1[3]};
            bf16x8 pfv = (kc == 0) ? pf0 : (kc == 1) ? pf1 : (kc == 2) ? pf2 : pf3;
            ot0 = __builtin_amdgcn_mfma_f32_32x32x16_bf16(__builtin_bit_cast(bf16x8, g0), pfv, ot0, 0, 0, 0);
            ot1 = __builtin_amdgcn_mfma_f32_32x32x16_bf16(__builtin_bit_cast(bf16x8, g1), pfv, ot1, 0, 0, 0);
        }
        __builtin_amdgcn_s_setprio(0);

        if (t + 1 < SEQ / 64) stage_write(cur ^ 1);
        __syncthreads();
        cur ^= 1;
    }

    // epilogue: O[q][d] = O^T / l, to [B,S,DIM] bf16
    const float inv = 1.0f / l;
    const int b = bh >> 4, h = bh & 15;
    unsigned short* orow = O + ((size_t)(b * SEQ + qrow)) * DIM + h * HD;
    #pragma unroll
    for (int tg = 0; tg < 4; ++tg) {
        unsigned wA, wB;
        CVTPK(wA, ot0[4 * tg + 0] * inv, ot0[4 * tg + 1] * inv);
        CVTPK(wB, ot0[4 * tg + 2] * inv, ot0[4 * tg + 3] * inv);
        u32x2 wlo = {wA, wB};
        *(u32x2*)(orow + 8 * tg + 4 * hi) = wlo;
        CVTPK(wA, ot1[4 * tg + 0] * inv, ot1[4 * tg + 1] * inv);
        CVTPK(wB, ot1[4 * tg + 2] * inv, ot1[4 * tg + 3] * inv);
        u32x2 whi = {wA, wB};
        *(u32x2*)(orow + 32 + 8 * tg + 4 * hi) = whi;
    }
}

extern "C" void kernel_launch(void* const* d_in, const int* in_sizes, int n_in,
                              void* d_out, int out_size, void* d_ws, size_t ws_size,
                              hipStream_t stream) {
    const float* x  = (const float*)d_in[0];
    const float* Wq = (const float*)d_in[1];
    const float* Wk = (const float*)d_in[2];
    const float* Wv = (const float*)d_in[3];
    const float* Wo = (const float*)d_in[4];
    const float* bo = (const float*)d_in[5];
    float* out = (float*)d_out;

    unsigned short* ws = (unsigned short*)d_ws;
    unsigned short* xb  = ws;
    unsigned short* wqb = xb + (size_t)MTOT * DIM;
    unsigned short* wkb = wqb + (size_t)DIM * DIM;
    unsigned short* wvb = wkb + (size_t)DIM * DIM;
    unsigned short* wob = wvb + (size_t)DIM * DIM;
    unsigned short* qb  = wob + (size_t)DIM * DIM;
    unsigned short* kb  = qb + (size_t)MTOT * DIM;
    unsigned short* vb  = kb + (size_t)MTOT * DIM;
    unsigned short* ob  = vb + (size_t)MTOT * DIM;

    cast_kernel<<<dim3(MTOT * DIM / 1024), 256, 0, stream>>>(x, xb, MTOT * DIM);
    cast_kernel<<<dim3(DIM * DIM / 1024), 256, 0, stream>>>(Wq, wqb, DIM * DIM);
    cast_kernel<<<dim3(DIM * DIM / 1024), 256, 0, stream>>>(Wk, wkb, DIM * DIM);
    cast_kernel<<<dim3(DIM * DIM / 1024), 256, 0, stream>>>(Wv, wvb, DIM * DIM);
    cast_kernel<<<dim3(DIM * DIM / 1024), 256, 0, stream>>>(Wo, wob, DIM * DIM);

    gemm_nt<0><<<dim3(DIM / 128, MTOT / 128, 3), 256, 0, stream>>>(
        xb, wqb, wkb, wvb, qb, kb, vb, nullptr, nullptr);

    attn_kernel<<<dim3(256), 512, 0, stream>>>(qb, kb, vb, ob);

    gemm_nt<1><<<dim3(DIM / 128, MTOT / 128, 1), 256, 0, stream>>>(
        ob, wob, nullptr, nullptr, nullptr, nullptr, nullptr, out, bo);
}